// Round 10
// baseline (358.808 us; speedup 1.0000x reference)
//
#include <hip/hip_runtime.h>

typedef __bf16 bf16;
typedef __bf16 bf16x8 __attribute__((ext_vector_type(8)));
typedef float f32x4 __attribute__((ext_vector_type(4)));

#define MFMA16(a,b,c) __builtin_amdgcn_mfma_f32_16x16x32_bf16(a,b,c,0,0,0)

#if __has_builtin(__builtin_amdgcn_exp2f)
#define EXP2(x) __builtin_amdgcn_exp2f(x)
#else
#define EXP2(x) exp2f(x)
#endif

// global -> LDS direct copy, 16B per lane; LDS dest is wave-uniform base + lane*16
#define GLOAD16(g, l) __builtin_amdgcn_global_load_lds( \
    (const __attribute__((address_space(1))) void*)(g), \
    (__attribute__((address_space(3))) void*)(l), 16, 0, 0)

#define N_Q   4096
#define DFEAT 512
#define KQ    8192
#define NLAB  128
#define NHEAD 8
#define KVB   32

// ---------------- workspace layout (bytes) ----------------
#define MBv (1024ull*1024ull)
#define OFF_COUNTS 0ull
#define OFF_FLAGS  1024ull
#define OFF_SEL    (64ull*1024ull)
#define OFF_FQ1    (1ull*MBv)   // 8192x512 bf16 = 8MB   (fq2 adjacent)
#define OFF_FQ2    (9ull*MBv)
#define OFF_LQ1    (17ull*MBv)  // 8192x128 bf16 = 2MB   (lq2 adjacent)
#define OFF_LQ2    (19ull*MBv)
#define OFF_Q1     (21ull*MBv)  // 4096x512 bf16 = 4MB
#define OFF_Q2     (25ull*MBv)
#define OFF_K1     (29ull*MBv)  // 16384x512 bf16 = 16MB (both streams)
#define OFF_WQT    (45ull*MBv)
#define OFF_WKT    (46ull*MBv)
#define OFF_WOT    (47ull*MBv)
#define OFF_VWT    (48ull*MBv)  // 128x16384 bf16 = 4MB (VW^T, natural layout, both streams)
#define OFF_ACC    (52ull*MBv)  // 2x4096x128 f32 = 4MB

// ---------------- inline dtype probe ----------------
__device__ __forceinline__ int probe_f32(const void* p) {
    const unsigned short* u = (const unsigned short*)p;
    int bad = 0;
    #pragma unroll
    for (int i = 0; i < 32; i++) {
        unsigned short v = u[2 * i];
        int e = (v >> 7) & 0xFF;
        if (e > 140 || (e < 60 && e != 0)) bad++;
    }
    return bad > 3;
}

// ---------------- dtype-agnostic loads ----------------
__device__ __forceinline__ float loads(const void* p, size_t i, int f32m) {
    return f32m ? ((const float*)p)[i] : (float)((const bf16*)p)[i];
}
__device__ __forceinline__ bf16x8 load8(const void* p, size_t i, int f32m) {
    bf16x8 r;
    if (f32m) {
        const float4* q = (const float4*)((const float*)p + i);
        float4 f0 = q[0], f1 = q[1];
        r[0] = (bf16)f0.x; r[1] = (bf16)f0.y; r[2] = (bf16)f0.z; r[3] = (bf16)f0.w;
        r[4] = (bf16)f1.x; r[5] = (bf16)f1.y; r[6] = (bf16)f1.z; r[7] = (bf16)f1.w;
    } else {
        r = *(const bf16x8*)((const bf16*)p + i);
    }
    return r;
}

// ---------------- prep: flags + transposes + accb zeroing, one launch ----------------
// Grid: [0,2048) flags | [2048,2304) Wq | [2304,2560) Wk | [2560,2576) Wo | [2576,3600) zero accb
__device__ __forceinline__ void do_transpose(const void* W, bf16* T, int n,
                                             int bxi, int byi, int f32m, bf16 (*tile)[33]) {
    int bx = bxi * 32, by = byi * 32;
    int tx = threadIdx.x & 31, ty = threadIdx.x >> 5;
    for (int r = ty; r < 32; r += 8) tile[r][tx] = (bf16)loads(W, (size_t)(by + r) * n + bx + tx, f32m);
    __syncthreads();
    for (int r = ty; r < 32; r += 8) T[(size_t)(bx + r) * n + by + tx] = tile[tx][r];
}

__global__ void prep_kernel(const void* __restrict__ Wq, const void* __restrict__ Wk,
                            const void* __restrict__ Wo,
                            bf16* __restrict__ wqT, bf16* __restrict__ wkT, bf16* __restrict__ woT,
                            const void* __restrict__ ulb1, const void* __restrict__ ulb2,
                            int* __restrict__ flags, float* __restrict__ accb,
                            const void* __restrict__ probe) {
    __shared__ bf16 tile[32][33];
    int b = blockIdx.x, t = threadIdx.x;
    if (b >= 2576) {                // zero accb: 1024 blocks x 256 thr x 1 float4
        float4 z = {0.f, 0.f, 0.f, 0.f};
        ((float4*)accb)[(size_t)(b - 2576) * 256 + t] = z;
        return;
    }
    int f32m = probe_f32(probe);
    if (b < 2048) {                 // flags: 4 rows per block (one per wave)
        int idx = b * 4 + (t >> 6); // [0, 8192)
        int lane = t & 63;
        int s = idx >> 12, row = idx & 4095;
        const void* p = s ? ulb2 : ulb1;
        size_t base = (size_t)row * NLAB;
        float m = fmaxf(loads(p, base + lane, f32m), loads(p, base + lane + 64, f32m));
        #pragma unroll
        for (int off = 32; off; off >>= 1) m = fmaxf(m, __shfl_xor(m, off));
        if (lane == 0) flags[s * N_Q + row] = (m > 0.95f) ? 1 : 0;
    } else if (b < 2304) {          // Wq: 16x16 blocks of 512^2
        int tb = b - 2048;
        do_transpose(Wq, wqT, 512, tb & 15, tb >> 4, f32m, tile);
    } else if (b < 2560) {          // Wk
        int tb = b - 2304;
        do_transpose(Wk, wkT, 512, tb & 15, tb >> 4, f32m, tile);
    } else {                        // Wo: 4x4 blocks of 128^2
        int tb = b - 2560;
        do_transpose(Wo, woT, 128, tb & 3, tb >> 2, f32m, tile);
    }
}

// ---------------- scan: stable compaction ----------------
__global__ void scan_kernel(const int* __restrict__ flags, int* __restrict__ sel,
                            int* __restrict__ counts) {
    int s = blockIdx.x, t = threadIdx.x; // 1024 threads
    const int* f = flags + s * N_Q;
    int* selp = sel + s * N_Q;
    __shared__ int ls[1024];
    int f0 = f[t*4], f1 = f[t*4+1], f2 = f[t*4+2], f3 = f[t*4+3];
    int local = f0 + f1 + f2 + f3;
    ls[t] = local;
    __syncthreads();
    for (int off = 1; off < 1024; off <<= 1) {
        int v = (t >= off) ? ls[t - off] : 0;
        __syncthreads();
        ls[t] += v;
        __syncthreads();
    }
    int pos = ls[t] - local;
    if (f0) selp[pos++] = t*4;
    if (f1) selp[pos++] = t*4+1;
    if (f2) selp[pos++] = t*4+2;
    if (f3) selp[pos++] = t*4+3;
    if (t == 1023) counts[s] = ls[1023];
}

// ---------------- build queues ----------------
__global__ void buildq_kernel(const void* __restrict__ anchor, const void* __restrict__ positive,
                              const void* __restrict__ lbfeat, const void* __restrict__ lboh,
                              const void* __restrict__ ulb1, const void* __restrict__ ulb2,
                              const void* __restrict__ fq1i, const void* __restrict__ fq2i,
                              const void* __restrict__ lq1i, const void* __restrict__ lq2i,
                              const int* __restrict__ sel, const int* __restrict__ counts,
                              bf16* __restrict__ fq1o, bf16* __restrict__ fq2o,
                              bf16* __restrict__ lq1o, bf16* __restrict__ lq2o,
                              const void* __restrict__ probe) {
    int f32m = probe_f32(probe);
    int i = blockIdx.x, s = blockIdx.y, t = threadIdx.x; // 128 threads
    int C = counts[s];
    const void *fb, *lb;
    size_t frow, lrow;
    if (i < C) {
        int r = sel[s * N_Q + i];
        fb = s ? positive : anchor; frow = r;
        lb = s ? ulb2 : ulb1;       lrow = r;
    } else if (i < C + 512) {
        int r = i - C + s * 512;
        fb = lbfeat; frow = r;
        lb = lboh;   lrow = r;
    } else {
        int r = i - C - 512;
        fb = s ? fq2i : fq1i; frow = r;
        lb = s ? lq2i : lq1i; lrow = r;
    }
    bf16* fd = (s ? fq2o : fq1o) + (size_t)i * DFEAT;
    bf16* ld = (s ? lq2o : lq1o) + (size_t)i * NLAB;
    if (t < 64)      *(bf16x8*)&fd[t * 8]        = load8(fb, frow * DFEAT + (size_t)t * 8, f32m);
    else if (t < 80) *(bf16x8*)&ld[(t - 64) * 8] = load8(lb, lrow * NLAB + (size_t)(t - 64) * 8, f32m);
}

// ---------------- merged GEMM: q-proj (2 streams) + k-proj + VW^T in one launch ----------------
__device__ __forceinline__ void gemm_body(const void* __restrict__ A, const bf16* __restrict__ B,
                                          bf16* __restrict__ C, int N, int Kd, float alpha,
                                          int f32m, int m0, int n0,
                                          bf16* As, bf16* Bs) {
    int t = threadIdx.x, lane = t & 63, wid = t >> 6;
    int quad = lane >> 4, l15 = lane & 15;
    int wrow = (wid >> 1) * 64, wcol = (wid & 1) * 64;
    int srow = t >> 1, sseg = t & 1;
    f32x4 acc[4][4] = {};
    for (int k0 = 0; k0 < Kd; k0 += 32) {
        __syncthreads();
        bf16x8 a0 = load8(A, (size_t)(m0 + srow) * Kd + k0 + sseg * 8, f32m);
        bf16x8 a1 = load8(A, (size_t)(m0 + srow) * Kd + k0 + (sseg + 2) * 8, f32m);
        const uint4* gb = (const uint4*)(B + (size_t)(n0 + srow) * Kd + k0);
        uint4 b0 = gb[sseg], b1 = gb[sseg + 2];
        *(bf16x8*)&As[srow * 72 + sseg * 8]       = a0;
        *(bf16x8*)&As[srow * 72 + (sseg + 2) * 8] = a1;
        *(uint4*)&Bs[srow * 72 + sseg * 8]        = b0;
        *(uint4*)&Bs[srow * 72 + (sseg + 2) * 8]  = b1;
        __syncthreads();
        bf16x8 af[4], bfr[4];
        #pragma unroll
        for (int mt = 0; mt < 4; mt++) af[mt]  = *(const bf16x8*)&As[(wrow + mt*16 + l15) * 72 + quad * 8];
        #pragma unroll
        for (int nt = 0; nt < 4; nt++) bfr[nt] = *(const bf16x8*)&Bs[(wcol + nt*16 + l15) * 72 + quad * 8];
        #pragma unroll
        for (int mt = 0; mt < 4; mt++)
            #pragma unroll
            for (int nt = 0; nt < 4; nt++)
                acc[mt][nt] = MFMA16(af[mt], bfr[nt], acc[mt][nt]);
    }
    #pragma unroll
    for (int mt = 0; mt < 4; mt++)
        #pragma unroll
        for (int nt = 0; nt < 4; nt++)
            #pragma unroll
            for (int r = 0; r < 4; r++) {
                int row = m0 + wrow + mt*16 + quad*4 + r;
                int col = n0 + wcol + nt*16 + l15;
                C[(size_t)row * N + col] = (bf16)(acc[mt][nt][r] * alpha);
            }
}

// Grid: [0,256) q-proj | [256,768) k-proj | [768,896) VW^T
// (256,3): 36KB LDS + ~115 VGPR fit 3 blocks/CU -> 896 blocks in ~1.2 rounds instead of 1.75
__launch_bounds__(256, 3)
__global__ void gemm3_kernel(const void* __restrict__ anchor, const void* __restrict__ positive,
                             const bf16* __restrict__ fq1, const bf16* __restrict__ woT,
                             const bf16* __restrict__ lq1,
                             const bf16* __restrict__ wqT, const bf16* __restrict__ wkT,
                             bf16* __restrict__ q1, bf16* __restrict__ q2,
                             bf16* __restrict__ k1, bf16* __restrict__ vwt,
                             const void* __restrict__ probe) {
    __shared__ __align__(16) bf16 As[128 * 72];
    __shared__ __align__(16) bf16 Bs[128 * 72];
    int b = blockIdx.x;
    if (b < 256) {
        int f32m = probe_f32(probe);
        int s = b >> 7, r = b & 127;
        gemm_body(s ? positive : anchor, wqT, s ? q2 : q1, 512, 512,
                  0.125f * 1.44269504088896f, f32m, (r >> 2) * 128, (r & 3) * 128, As, Bs);
    } else if (b < 768) {
        int r = b - 256;
        gemm_body(fq1, wkT, k1, 512, 512, 1.0f, 0, (r >> 2) * 128, (r & 3) * 128, As, Bs);
    } else {
        int r = b - 768;
        gemm_body(woT, lq1, vwt, 16384, 128, 1.0f, 0, 0, r * 128, As, Bs);
    }
}

// ---------------- flash v6 (R6-exact, proven 195.5us): 64-row waves + kv-split pairs ----------
__launch_bounds__(256, 2)
__global__ void flash3_kernel(const bf16* __restrict__ q1, const bf16* __restrict__ q2,
                              const bf16* __restrict__ kbase, const bf16* __restrict__ vbase,
                              float* __restrict__ acc_out) {
    __shared__ __align__(16) char smem[49152];   // 16KB K (2 half x 2 buf x 4KB) + 32KB V (2x2x8KB)
    int qb = blockIdx.x, h = blockIdx.y, s = blockIdx.z;
    const bf16* Q  = s ? q2 : q1;
    const bf16* Kp = kbase + (size_t)s * KQ * DFEAT + h * 64;
    const bf16* Vp = vbase + (size_t)s * KQ;          // row pitch 2*KQ
    int t = threadIdx.x, lane = t & 63, wid = t >> 6;
    int quad = lane >> 4, l15 = lane & 15;
    int wq = wid & 1, wh = wid >> 1;
    int qbase = qb * 128 + wq * 64;

    // Q B-frags in registers for whole kernel (4 m-tiles x 2 feat chunks)
    bf16x8 qf[4][2];
    #pragma unroll
    for (int mt = 0; mt < 4; mt++)
        #pragma unroll
        for (int ch = 0; ch < 2; ch++)
            qf[mt][ch] = *(const bf16x8*)(Q + (size_t)(qbase + mt*16 + l15) * DFEAT + h*64 + ch*32 + quad*8);

    bf16x8 onesf;
    #pragma unroll
    for (int i = 0; i < 8; i++) onesf[i] = (bf16)1.0f;

    // LDS tile bases
    bf16* Kt = (bf16*)smem;            // tile stride 2048 elems (4KB)
    bf16* Vt = (bf16*)(smem + 16384);  // tile stride 4096 elems (8KB)

    // staging lane constants: linear LDS slot = lane&7 of row lane>>3; logical slot = lslot ^ (row&7)
    int srow8 = lane >> 3;
    int sslot = (lane & 7) ^ srow8;
    const bf16* KgH = Kp + (size_t)(wh * 4096) * DFEAT + (size_t)srow8 * DFEAT + sslot * 8;
    const bf16* VgH = Vp + wh * 4096 + (size_t)(2*srow8 + (sslot >> 2)) * (2 * KQ) + (sslot & 3) * 8;

    // read offset maps
    const int h7 = l15 & 7;
    int kro[2][2], vro[8];
    #pragma unroll
    for (int nt = 0; nt < 2; nt++)
        #pragma unroll
        for (int ch = 0; ch < 2; ch++)
            kro[nt][ch] = (nt*16 + l15) * 64 + (((ch*4 + quad) ^ h7) << 3);
    #pragma unroll
    for (int ct = 0; ct < 8; ct++)
        vro[ct] = (ct*8 + (l15 >> 1)) * 64 + (((((l15 & 1) << 2) | quad) ^ (l15 >> 1)) << 3);

    // prologue: stage it=0 into buf 0
    {
        bf16* kb = Kt + (size_t)(wh*2 + 0) * 2048;
        bf16* vb = Vt + (size_t)(wh*2 + 0) * 4096;
        if (wq == 0) {
            #pragma unroll
            for (int c = 0; c < 4; c++) GLOAD16(KgH + (size_t)c*8*DFEAT, kb + c*512);
            #pragma unroll
            for (int c = 0; c < 2; c++) GLOAD16(VgH + (size_t)c*16*(2*KQ), vb + c*512);
        } else {
            #pragma unroll
            for (int c = 2; c < 8; c++) GLOAD16(VgH + (size_t)c*16*(2*KQ), vb + c*512);
        }
    }
    __syncthreads();

    f32x4 O[4][8] = {};
    f32x4 L[4] = {};

    for (int it = 0; it < 4096 / KVB; it++) {
        int p = it & 1;
        // stage next iter into other buffer (loads complete before next barrier's vmcnt(0))
        if (it + 1 < 4096 / KVB) {
            int kvn = (it + 1) * KVB;
            bf16* kb = Kt + (size_t)(wh*2 + (p^1)) * 2048;
            bf16* vb = Vt + (size_t)(wh*2 + (p^1)) * 4096;
            if (wq == 0) {
                #pragma unroll
                for (int c = 0; c < 4; c++) GLOAD16(KgH + (size_t)kvn*DFEAT + (size_t)c*8*DFEAT, kb + c*512);
                #pragma unroll
                for (int c = 0; c < 2; c++) GLOAD16(VgH + kvn + (size_t)c*16*(2*KQ), vb + c*512);
            } else {
                #pragma unroll
                for (int c = 2; c < 8; c++) GLOAD16(VgH + kvn + (size_t)c*16*(2*KQ), vb + c*512);
            }
        }
        const bf16* Kb = Kt + (size_t)(wh*2 + p) * 2048;
        const bf16* Vb = Vt + (size_t)(wh*2 + p) * 4096;

        // K fragments (full 32x64 tile)
        bf16x8 kf[2][2];
        #pragma unroll
        for (int nt = 0; nt < 2; nt++)
            #pragma unroll
            for (int ch = 0; ch < 2; ch++)
                kf[nt][ch] = *(const bf16x8*)&Kb[kro[nt][ch]];

        // QK + exp fused per mt: S^T = K . Q^T, D[m=kv][n=q]
        bf16x8 P[4];
        __builtin_amdgcn_s_setprio(1);
        #pragma unroll
        for (int mt = 0; mt < 4; mt++) {
            f32x4 s0 = {}, s1 = {};
            s0 = MFMA16(kf[0][0], qf[mt][0], s0);
            s0 = MFMA16(kf[0][1], qf[mt][1], s0);
            s1 = MFMA16(kf[1][0], qf[mt][0], s1);
            s1 = MFMA16(kf[1][1], qf[mt][1], s1);
            bf16x8 pp;
            #pragma unroll
            for (int r = 0; r < 4; r++) {
                pp[r]     = (bf16)EXP2(s0[r]);
                pp[4 + r] = (bf16)EXP2(s1[r]);
            }
            P[mt] = pp;
        }
        // row-sums via ones-MFMA
        #pragma unroll
        for (int mt = 0; mt < 4; mt++) L[mt] = MFMA16(P[mt], onesf, L[mt]);
        // O += P . VW  (V frags JIT from LDS)
        #pragma unroll
        for (int ct = 0; ct < 8; ct++) {
            bf16x8 vf = *(const bf16x8*)&Vb[vro[ct]];
            #pragma unroll
            for (int mt = 0; mt < 4; mt++)
                O[mt][ct] = MFMA16(P[mt], vf, O[mt][ct]);
        }
        __builtin_amdgcn_s_setprio(0);
        __syncthreads();
    }

    // merge kv-halves through LDS (two passes to fit 48KB), then normalize + atomicAdd
    f32x4* MP = (f32x4*)smem;
    int midx = lane * 36;
    #pragma unroll
    for (int pass = 0; pass < 2; pass++) {
        if (wh == 1 && wq == pass) {
            #pragma unroll
            for (int mt = 0; mt < 4; mt++) {
                #pragma unroll
                for (int ct = 0; ct < 8; ct++) MP[midx + mt*8 + ct] = O[mt][ct];
                MP[midx + 32 + mt] = L[mt];
            }
        }
        __syncthreads();
        if (wh == 0 && wq == pass) {
            #pragma unroll
            for (int mt = 0; mt < 4; mt++) {
                f32x4 lp = MP[midx + 32 + mt];
                float invr[4];
                #pragma unroll
                for (int r = 0; r < 4; r++) invr[r] = 1.0f / (8.0f * (L[mt][r] + lp[r]));
                #pragma unroll
                for (int ct = 0; ct < 8; ct++) {
                    f32x4 op = MP[midx + mt*8 + ct];
                    #pragma unroll
                    for (int r = 0; r < 4; r++) {
                        int row = qbase + mt*16 + quad*4 + r;
                        atomicAdd(&acc_out[((size_t)s * N_Q + row) * NLAB + ct*16 + l15],
                                  (O[mt][ct][r] + op[r]) * invr[r]);
                    }
                }
            }
        }
        __syncthreads();
    }
}

// ---------------- bias + cast ----------------
__global__ void bias_kernel(const float* __restrict__ acc, const void* __restrict__ bo,
                            void* __restrict__ out, const void* __restrict__ probe) {
    int f32m = probe_f32(probe);
    int idx = blockIdx.x * 256 + threadIdx.x;
    float v = acc[idx] + loads(bo, idx & (NLAB - 1), f32m);
    if (f32m) ((float*)out)[idx] = v;
    else      ((bf16*)out)[idx] = (bf16)v;
}

extern "C" void kernel_launch(void* const* d_in, const int* in_sizes, int n_in,
                              void* d_out, int out_size, void* d_ws, size_t ws_size,
                              hipStream_t stream) {
    const void* anchor   = d_in[0];
    const void* positive = d_in[1];
    const void* lbfeat   = d_in[2];
    const void* lboh     = d_in[3];
    const void* ulb1     = d_in[5];
    const void* ulb2     = d_in[6];
    const void* fq1i     = d_in[7];
    const void* fq2i     = d_in[8];
    const void* lq1i     = d_in[9];
    const void* lq2i     = d_in[10];
    const void* Wq       = d_in[11];
    const void* Wk       = d_in[12];
    const void* Wo       = d_in[13];
    const void* bo       = d_in[14];

    char* ws = (char*)d_ws;
    int*  counts = (int*)(ws + OFF_COUNTS);
    int*  flags  = (int*)(ws + OFF_FLAGS);
    int*  sel    = (int*)(ws + OFF_SEL);
    bf16* fq1  = (bf16*)(ws + OFF_FQ1);
    bf16* fq2  = (bf16*)(ws + OFF_FQ2);
    bf16* lq1  = (bf16*)(ws + OFF_LQ1);
    bf16* lq2  = (bf16*)(ws + OFF_LQ2);
    bf16* q1   = (bf16*)(ws + OFF_Q1);
    bf16* q2   = (bf16*)(ws + OFF_Q2);
    bf16* k1   = (bf16*)(ws + OFF_K1);
    bf16* wqT  = (bf16*)(ws + OFF_WQT);
    bf16* wkT  = (bf16*)(ws + OFF_WKT);
    bf16* woT  = (bf16*)(ws + OFF_WOT);
    bf16* vwt  = (bf16*)(ws + OFF_VWT);
    float* accb = (float*)(ws + OFF_ACC);

    // flags + 3 weight transposes + accb zeroing (dtype probe inlined)
    prep_kernel<<<3600, 256, 0, stream>>>(Wq, Wk, Wo, wqT, wkT, woT,
                                          ulb1, ulb2, flags, accb, anchor);
    scan_kernel<<<2, 1024, 0, stream>>>(flags, sel, counts);
    buildq_kernel<<<dim3(KQ, 2), 128, 0, stream>>>(anchor, positive, lbfeat, lboh, ulb1, ulb2,
                                                   fq1i, fq2i, lq1i, lq2i, sel, counts,
                                                   fq1, fq2, lq1, lq2, anchor);
    // q-proj (2 streams) + k-proj + VW^T in one launch
    gemm3_kernel<<<896, 256, 0, stream>>>(anchor, positive, fq1, woT, lq1, wqT, wkT,
                                          q1, q2, k1, vwt, anchor);

    flash3_kernel<<<dim3(32, NHEAD, 2), 256, 0, stream>>>(q1, q2, k1, vwt, accb);
    bias_kernel<<<(2 * N_Q * NLAB) / 256, 256, 0, stream>>>(accb, bo, d_out, anchor);
}

// Round 12
// 346.549 us; speedup vs baseline: 1.0354x; 1.0354x over previous
//
#include <hip/hip_runtime.h>

typedef __bf16 bf16;
typedef __bf16 bf16x8 __attribute__((ext_vector_type(8)));
typedef float f32x4 __attribute__((ext_vector_type(4)));

#define MFMA16(a,b,c) __builtin_amdgcn_mfma_f32_16x16x32_bf16(a,b,c,0,0,0)

#if __has_builtin(__builtin_amdgcn_exp2f)
#define EXP2(x) __builtin_amdgcn_exp2f(x)
#else
#define EXP2(x) exp2f(x)
#endif

// global -> LDS direct copy, 16B per lane; LDS dest is wave-uniform base + lane*16
#define GLOAD16(g, l) __builtin_amdgcn_global_load_lds( \
    (const __attribute__((address_space(1))) void*)(g), \
    (__attribute__((address_space(3))) void*)(l), 16, 0, 0)

#define N_Q   4096
#define DFEAT 512
#define KQ    8192
#define NLAB  128
#define NHEAD 8
#define KVB   32

// ---------------- workspace layout (bytes) ----------------
#define MBv (1024ull*1024ull)
#define OFF_COUNTS 0ull
#define OFF_MODE   512ull
#define OFF_FLAGS  1024ull
#define OFF_SEL    (64ull*1024ull)
#define OFF_FQ1    (1ull*MBv)   // 8192x512 bf16 = 8MB   (fq2 adjacent)
#define OFF_FQ2    (9ull*MBv)
#define OFF_LQ1    (17ull*MBv)  // 8192x128 bf16 = 2MB   (lq2 adjacent)
#define OFF_LQ2    (19ull*MBv)
#define OFF_Q1     (21ull*MBv)  // 4096x512 bf16 = 4MB
#define OFF_Q2     (25ull*MBv)
#define OFF_K1     (29ull*MBv)  // 16384x512 bf16 = 16MB (both streams)
#define OFF_WQT    (45ull*MBv)
#define OFF_WKT    (46ull*MBv)
#define OFF_WOT    (47ull*MBv)
#define OFF_VWT    (48ull*MBv)  // 128x16384 bf16 = 4MB (VW^T, natural layout, both streams)
#define OFF_ACC    (52ull*MBv)  // 2x4096x128 f32 = 4MB

// ---------------- inline dtype probe (used once, in prep) ----------------
__device__ __forceinline__ int probe_f32(const void* p) {
    const unsigned short* u = (const unsigned short*)p;
    int bad = 0;
    #pragma unroll
    for (int i = 0; i < 32; i++) {
        unsigned short v = u[2 * i];
        int e = (v >> 7) & 0xFF;
        if (e > 140 || (e < 60 && e != 0)) bad++;
    }
    return bad > 3;
}

// ---------------- dtype-agnostic loads ----------------
__device__ __forceinline__ float loads(const void* p, size_t i, int f32m) {
    return f32m ? ((const float*)p)[i] : (float)((const bf16*)p)[i];
}
__device__ __forceinline__ bf16x8 load8(const void* p, size_t i, int f32m) {
    bf16x8 r;
    if (f32m) {
        const float4* q = (const float4*)((const float*)p + i);
        float4 f0 = q[0], f1 = q[1];
        r[0] = (bf16)f0.x; r[1] = (bf16)f0.y; r[2] = (bf16)f0.z; r[3] = (bf16)f0.w;
        r[4] = (bf16)f1.x; r[5] = (bf16)f1.y; r[6] = (bf16)f1.z; r[7] = (bf16)f1.w;
    } else {
        r = *(const bf16x8*)((const bf16*)p + i);
    }
    return r;
}

// ---------------- prep: flags + transposes + accb zeroing + mode publish ----------------
// Grid: [0,2048) flags | [2048,2304) Wq | [2304,2560) Wk | [2560,2576) Wo | [2576,3600) zero accb
__device__ __forceinline__ void do_transpose(const void* W, bf16* T, int n,
                                             int bxi, int byi, int f32m, bf16 (*tile)[33]) {
    int bx = bxi * 32, by = byi * 32;
    int tx = threadIdx.x & 31, ty = threadIdx.x >> 5;
    for (int r = ty; r < 32; r += 8) tile[r][tx] = (bf16)loads(W, (size_t)(by + r) * n + bx + tx, f32m);
    __syncthreads();
    for (int r = ty; r < 32; r += 8) T[(size_t)(bx + r) * n + by + tx] = tile[tx][r];
}

__global__ void prep_kernel(const void* __restrict__ Wq, const void* __restrict__ Wk,
                            const void* __restrict__ Wo,
                            bf16* __restrict__ wqT, bf16* __restrict__ wkT, bf16* __restrict__ woT,
                            const void* __restrict__ ulb1, const void* __restrict__ ulb2,
                            int* __restrict__ flags, float* __restrict__ accb,
                            int* __restrict__ modep, const void* __restrict__ probe) {
    __shared__ bf16 tile[32][33];
    int b = blockIdx.x, t = threadIdx.x;
    if (b >= 2576) {                // zero accb: 1024 blocks x 256 thr x 1 float4
        float4 z = {0.f, 0.f, 0.f, 0.f};
        ((float4*)accb)[(size_t)(b - 2576) * 256 + t] = z;
        return;
    }
    int f32m = probe_f32(probe);
    if (b == 0 && t == 0) *modep = f32m;    // publish for downstream kernels
    if (b < 2048) {                 // flags: 4 rows per block (one per wave)
        int idx = b * 4 + (t >> 6); // [0, 8192)
        int lane = t & 63;
        int s = idx >> 12, row = idx & 4095;
        const void* p = s ? ulb2 : ulb1;
        size_t base = (size_t)row * NLAB;
        float m = fmaxf(loads(p, base + lane, f32m), loads(p, base + lane + 64, f32m));
        #pragma unroll
        for (int off = 32; off; off >>= 1) m = fmaxf(m, __shfl_xor(m, off));
        if (lane == 0) flags[s * N_Q + row] = (m > 0.95f) ? 1 : 0;
    } else if (b < 2304) {          // Wq: 16x16 blocks of 512^2
        int tb = b - 2048;
        do_transpose(Wq, wqT, 512, tb & 15, tb >> 4, f32m, tile);
    } else if (b < 2560) {          // Wk
        int tb = b - 2304;
        do_transpose(Wk, wkT, 512, tb & 15, tb >> 4, f32m, tile);
    } else {                        // Wo: 4x4 blocks of 128^2
        int tb = b - 2560;
        do_transpose(Wo, woT, 128, tb & 3, tb >> 2, f32m, tile);
    }
}

// ---------------- scan: stable compaction ----------------
__global__ void scan_kernel(const int* __restrict__ flags, int* __restrict__ sel,
                            int* __restrict__ counts) {
    int s = blockIdx.x, t = threadIdx.x; // 1024 threads
    const int* f = flags + s * N_Q;
    int* selp = sel + s * N_Q;
    __shared__ int ls[1024];
    int f0 = f[t*4], f1 = f[t*4+1], f2 = f[t*4+2], f3 = f[t*4+3];
    int local = f0 + f1 + f2 + f3;
    ls[t] = local;
    __syncthreads();
    for (int off = 1; off < 1024; off <<= 1) {
        int v = (t >= off) ? ls[t - off] : 0;
        __syncthreads();
        ls[t] += v;
        __syncthreads();
    }
    int pos = ls[t] - local;
    if (f0) selp[pos++] = t*4;
    if (f1) selp[pos++] = t*4+1;
    if (f2) selp[pos++] = t*4+2;
    if (f3) selp[pos++] = t*4+3;
    if (t == 1023) counts[s] = ls[1023];
}

// ---------------- build queues ----------------
__global__ void buildq_kernel(const void* __restrict__ anchor, const void* __restrict__ positive,
                              const void* __restrict__ lbfeat, const void* __restrict__ lboh,
                              const void* __restrict__ ulb1, const void* __restrict__ ulb2,
                              const void* __restrict__ fq1i, const void* __restrict__ fq2i,
                              const void* __restrict__ lq1i, const void* __restrict__ lq2i,
                              const int* __restrict__ sel, const int* __restrict__ counts,
                              bf16* __restrict__ fq1o, bf16* __restrict__ fq2o,
                              bf16* __restrict__ lq1o, bf16* __restrict__ lq2o,
                              const int* __restrict__ modep) {
    int f32m = *modep;
    int i = blockIdx.x, s = blockIdx.y, t = threadIdx.x; // 128 threads
    int C = counts[s];
    const void *fb, *lb;
    size_t frow, lrow;
    if (i < C) {
        int r = sel[s * N_Q + i];
        fb = s ? positive : anchor; frow = r;
        lb = s ? ulb2 : ulb1;       lrow = r;
    } else if (i < C + 512) {
        int r = i - C + s * 512;
        fb = lbfeat; frow = r;
        lb = lboh;   lrow = r;
    } else {
        int r = i - C - 512;
        fb = s ? fq2i : fq1i; frow = r;
        lb = s ? lq2i : lq1i; lrow = r;
    }
    bf16* fd = (s ? fq2o : fq1o) + (size_t)i * DFEAT;
    bf16* ld = (s ? lq2o : lq1o) + (size_t)i * NLAB;
    if (t < 64)      *(bf16x8*)&fd[t * 8]        = load8(fb, frow * DFEAT + (size_t)t * 8, f32m);
    else if (t < 80) *(bf16x8*)&ld[(t - 64) * 8] = load8(lb, lrow * NLAB + (size_t)(t - 64) * 8, f32m);
}

// ---------------- merged GEMM: q-proj (2 streams) + k-proj + VW^T in one launch ----------------
__device__ __forceinline__ void gemm_body(const void* __restrict__ A, const bf16* __restrict__ B,
                                          bf16* __restrict__ C, int N, int Kd, float alpha,
                                          int f32m, int m0, int n0,
                                          bf16* As, bf16* Bs) {
    int t = threadIdx.x, lane = t & 63, wid = t >> 6;
    int quad = lane >> 4, l15 = lane & 15;
    int wrow = (wid >> 1) * 64, wcol = (wid & 1) * 64;
    int srow = t >> 1, sseg = t & 1;
    f32x4 acc[4][4] = {};
    for (int k0 = 0; k0 < Kd; k0 += 32) {
        __syncthreads();
        bf16x8 a0 = load8(A, (size_t)(m0 + srow) * Kd + k0 + sseg * 8, f32m);
        bf16x8 a1 = load8(A, (size_t)(m0 + srow) * Kd + k0 + (sseg + 2) * 8, f32m);
        const uint4* gb = (const uint4*)(B + (size_t)(n0 + srow) * Kd + k0);
        uint4 b0 = gb[sseg], b1 = gb[sseg + 2];
        *(bf16x8*)&As[srow * 72 + sseg * 8]       = a0;
        *(bf16x8*)&As[srow * 72 + (sseg + 2) * 8] = a1;
        *(uint4*)&Bs[srow * 72 + sseg * 8]        = b0;
        *(uint4*)&Bs[srow * 72 + (sseg + 2) * 8]  = b1;
        __syncthreads();
        bf16x8 af[4], bfr[4];
        #pragma unroll
        for (int mt = 0; mt < 4; mt++) af[mt]  = *(const bf16x8*)&As[(wrow + mt*16 + l15) * 72 + quad * 8];
        #pragma unroll
        for (int nt = 0; nt < 4; nt++) bfr[nt] = *(const bf16x8*)&Bs[(wcol + nt*16 + l15) * 72 + quad * 8];
        #pragma unroll
        for (int mt = 0; mt < 4; mt++)
            #pragma unroll
            for (int nt = 0; nt < 4; nt++)
                acc[mt][nt] = MFMA16(af[mt], bfr[nt], acc[mt][nt]);
    }
    #pragma unroll
    for (int mt = 0; mt < 4; mt++)
        #pragma unroll
        for (int nt = 0; nt < 4; nt++)
            #pragma unroll
            for (int r = 0; r < 4; r++) {
                int row = m0 + wrow + mt*16 + quad*4 + r;
                int col = n0 + wcol + nt*16 + l15;
                C[(size_t)row * N + col] = (bf16)(acc[mt][nt][r] * alpha);
            }
}

// Grid: [0,256) q-proj | [256,768) k-proj | [768,896) VW^T
__launch_bounds__(256, 3)
__global__ void gemm3_kernel(const void* __restrict__ anchor, const void* __restrict__ positive,
                             const bf16* __restrict__ fq1, const bf16* __restrict__ woT,
                             const bf16* __restrict__ lq1,
                             const bf16* __restrict__ wqT, const bf16* __restrict__ wkT,
                             bf16* __restrict__ q1, bf16* __restrict__ q2,
                             bf16* __restrict__ k1, bf16* __restrict__ vwt,
                             const int* __restrict__ modep) {
    __shared__ __align__(16) bf16 As[128 * 72];
    __shared__ __align__(16) bf16 Bs[128 * 72];
    int b = blockIdx.x;
    if (b < 256) {
        int f32m = *modep;
        int s = b >> 7, r = b & 127;
        gemm_body(s ? positive : anchor, wqT, s ? q2 : q1, 512, 512,
                  0.125f * 1.44269504088896f, f32m, (r >> 2) * 128, (r & 3) * 128, As, Bs);
    } else if (b < 768) {
        int r = b - 256;
        gemm_body(fq1, wkT, k1, 512, 512, 1.0f, 0, (r >> 2) * 128, (r & 3) * 128, As, Bs);
    } else {
        int r = b - 768;
        gemm_body(woT, lq1, vwt, 16384, 128, 1.0f, 0, 0, r * 128, As, Bs);
    }
}

// ---------------- flash v6 (R6-exact, proven ~193us): 64-row waves + kv-split pairs ----------
__launch_bounds__(256, 2)
__global__ void flash3_kernel(const bf16* __restrict__ q1, const bf16* __restrict__ q2,
                              const bf16* __restrict__ kbase, const bf16* __restrict__ vbase,
                              float* __restrict__ acc_out) {
    __shared__ __align__(16) char smem[49152];   // 16KB K (2 half x 2 buf x 4KB) + 32KB V (2x2x8KB)
    int qb = blockIdx.x, h = blockIdx.y, s = blockIdx.z;
    const bf16* Q  = s ? q2 : q1;
    const bf16* Kp = kbase + (size_t)s * KQ * DFEAT + h * 64;
    const bf16* Vp = vbase + (size_t)s * KQ;          // row pitch 2*KQ
    int t = threadIdx.x, lane = t & 63, wid = t >> 6;
    int quad = lane >> 4, l15 = lane & 15;
    int wq = wid & 1, wh = wid >> 1;
    int qbase = qb * 128 + wq * 64;

    // Q B-frags in registers for whole kernel (4 m-tiles x 2 feat chunks)
    bf16x8 qf[4][2];
    #pragma unroll
    for (int mt = 0; mt < 4; mt++)
        #pragma unroll
        for (int ch = 0; ch < 2; ch++)
            qf[mt][ch] = *(const bf16x8*)(Q + (size_t)(qbase + mt*16 + l15) * DFEAT + h*64 + ch*32 + quad*8);

    bf16x8 onesf;
    #pragma unroll
    for (int i = 0; i < 8; i++) onesf[i] = (bf16)1.0f;

    // LDS tile bases
    bf16* Kt = (bf16*)smem;            // tile stride 2048 elems (4KB)
    bf16* Vt = (bf16*)(smem + 16384);  // tile stride 4096 elems (8KB)

    // staging lane constants: linear LDS slot = lane&7 of row lane>>3; logical slot = lslot ^ (row&7)
    int srow8 = lane >> 3;
    int sslot = (lane & 7) ^ srow8;
    const bf16* KgH = Kp + (size_t)(wh * 4096) * DFEAT + (size_t)srow8 * DFEAT + sslot * 8;
    const bf16* VgH = Vp + wh * 4096 + (size_t)(2*srow8 + (sslot >> 2)) * (2 * KQ) + (sslot & 3) * 8;

    // read offset maps
    const int h7 = l15 & 7;
    int kro[2][2], vro[8];
    #pragma unroll
    for (int nt = 0; nt < 2; nt++)
        #pragma unroll
        for (int ch = 0; ch < 2; ch++)
            kro[nt][ch] = (nt*16 + l15) * 64 + (((ch*4 + quad) ^ h7) << 3);
    #pragma unroll
    for (int ct = 0; ct < 8; ct++)
        vro[ct] = (ct*8 + (l15 >> 1)) * 64 + (((((l15 & 1) << 2) | quad) ^ (l15 >> 1)) << 3);

    // prologue: stage it=0 into buf 0
    {
        bf16* kb = Kt + (size_t)(wh*2 + 0) * 2048;
        bf16* vb = Vt + (size_t)(wh*2 + 0) * 4096;
        if (wq == 0) {
            #pragma unroll
            for (int c = 0; c < 4; c++) GLOAD16(KgH + (size_t)c*8*DFEAT, kb + c*512);
            #pragma unroll
            for (int c = 0; c < 2; c++) GLOAD16(VgH + (size_t)c*16*(2*KQ), vb + c*512);
        } else {
            #pragma unroll
            for (int c = 2; c < 8; c++) GLOAD16(VgH + (size_t)c*16*(2*KQ), vb + c*512);
        }
    }
    __syncthreads();

    f32x4 O[4][8] = {};
    f32x4 L[4] = {};

    for (int it = 0; it < 4096 / KVB; it++) {
        int p = it & 1;
        // stage next iter into other buffer (loads complete before next barrier's vmcnt(0))
        if (it + 1 < 4096 / KVB) {
            int kvn = (it + 1) * KVB;
            bf16* kb = Kt + (size_t)(wh*2 + (p^1)) * 2048;
            bf16* vb = Vt + (size_t)(wh*2 + (p^1)) * 4096;
            if (wq == 0) {
                #pragma unroll
                for (int c = 0; c < 4; c++) GLOAD16(KgH + (size_t)kvn*DFEAT + (size_t)c*8*DFEAT, kb + c*512);
                #pragma unroll
                for (int c = 0; c < 2; c++) GLOAD16(VgH + kvn + (size_t)c*16*(2*KQ), vb + c*512);
            } else {
                #pragma unroll
                for (int c = 2; c < 8; c++) GLOAD16(VgH + kvn + (size_t)c*16*(2*KQ), vb + c*512);
            }
        }
        const bf16* Kb = Kt + (size_t)(wh*2 + p) * 2048;
        const bf16* Vb = Vt + (size_t)(wh*2 + p) * 4096;

        // K fragments (full 32x64 tile)
        bf16x8 kf[2][2];
        #pragma unroll
        for (int nt = 0; nt < 2; nt++)
            #pragma unroll
            for (int ch = 0; ch < 2; ch++)
                kf[nt][ch] = *(const bf16x8*)&Kb[kro[nt][ch]];

        // QK + exp fused per mt: S^T = K . Q^T, D[m=kv][n=q]
        bf16x8 P[4];
        __builtin_amdgcn_s_setprio(1);
        #pragma unroll
        for (int mt = 0; mt < 4; mt++) {
            f32x4 s0 = {}, s1 = {};
            s0 = MFMA16(kf[0][0], qf[mt][0], s0);
            s0 = MFMA16(kf[0][1], qf[mt][1], s0);
            s1 = MFMA16(kf[1][0], qf[mt][0], s1);
            s1 = MFMA16(kf[1][1], qf[mt][1], s1);
            bf16x8 pp;
            #pragma unroll
            for (int r = 0; r < 4; r++) {
                pp[r]     = (bf16)EXP2(s0[r]);
                pp[4 + r] = (bf16)EXP2(s1[r]);
            }
            P[mt] = pp;
        }
        // row-sums via ones-MFMA
        #pragma unroll
        for (int mt = 0; mt < 4; mt++) L[mt] = MFMA16(P[mt], onesf, L[mt]);
        // O += P . VW  (V frags JIT from LDS)
        #pragma unroll
        for (int ct = 0; ct < 8; ct++) {
            bf16x8 vf = *(const bf16x8*)&Vb[vro[ct]];
            #pragma unroll
            for (int mt = 0; mt < 4; mt++)
                O[mt][ct] = MFMA16(P[mt], vf, O[mt][ct]);
        }
        __builtin_amdgcn_s_setprio(0);
        __syncthreads();
    }

    // merge kv-halves through LDS (two passes to fit 48KB), then normalize + atomicAdd
    f32x4* MP = (f32x4*)smem;
    int midx = lane * 36;
    #pragma unroll
    for (int pass = 0; pass < 2; pass++) {
        if (wh == 1 && wq == pass) {
            #pragma unroll
            for (int mt = 0; mt < 4; mt++) {
                #pragma unroll
                for (int ct = 0; ct < 8; ct++) MP[midx + mt*8 + ct] = O[mt][ct];
                MP[midx + 32 + mt] = L[mt];
            }
        }
        __syncthreads();
        if (wh == 0 && wq == pass) {
            #pragma unroll
            for (int mt = 0; mt < 4; mt++) {
                f32x4 lp = MP[midx + 32 + mt];
                float invr[4];
                #pragma unroll
                for (int r = 0; r < 4; r++) invr[r] = 1.0f / (8.0f * (L[mt][r] + lp[r]));
                #pragma unroll
                for (int ct = 0; ct < 8; ct++) {
                    f32x4 op = MP[midx + mt*8 + ct];
                    #pragma unroll
                    for (int r = 0; r < 4; r++) {
                        int row = qbase + mt*16 + quad*4 + r;
                        atomicAdd(&acc_out[((size_t)s * N_Q + row) * NLAB + ct*16 + l15],
                                  (O[mt][ct][r] + op[r]) * invr[r]);
                    }
                }
            }
        }
        __syncthreads();
    }
}

// ---------------- bias + cast ----------------
__global__ void bias_kernel(const float* __restrict__ acc, const void* __restrict__ bo,
                            void* __restrict__ out, const int* __restrict__ modep) {
    int f32m = *modep;
    int idx = blockIdx.x * 256 + threadIdx.x;
    float v = acc[idx] + loads(bo, idx & (NLAB - 1), f32m);
    if (f32m) ((float*)out)[idx] = v;
    else      ((bf16*)out)[idx] = (bf16)v;
}

extern "C" void kernel_launch(void* const* d_in, const int* in_sizes, int n_in,
                              void* d_out, int out_size, void* d_ws, size_t ws_size,
                              hipStream_t stream) {
    const void* anchor   = d_in[0];
    const void* positive = d_in[1];
    const void* lbfeat   = d_in[2];
    const void* lboh     = d_in[3];
    const void* ulb1     = d_in[5];
    const void* ulb2     = d_in[6];
    const void* fq1i     = d_in[7];
    const void* fq2i     = d_in[8];
    const void* lq1i     = d_in[9];
    const void* lq2i     = d_in[10];
    const void* Wq       = d_in[11];
    const void* Wk       = d_in[12];
    const void* Wo       = d_in[13];
    const void* bo       = d_in[14];

    char* ws = (char*)d_ws;
    int*  counts = (int*)(ws + OFF_COUNTS);
    int*  modep  = (int*)(ws + OFF_MODE);
    int*  flags  = (int*)(ws + OFF_FLAGS);
    int*  sel    = (int*)(ws + OFF_SEL);
    bf16* fq1  = (bf16*)(ws + OFF_FQ1);
    bf16* fq2  = (bf16*)(ws + OFF_FQ2);
    bf16* lq1  = (bf16*)(ws + OFF_LQ1);
    bf16* lq2  = (bf16*)(ws + OFF_LQ2);
    bf16* q1   = (bf16*)(ws + OFF_Q1);
    bf16* q2   = (bf16*)(ws + OFF_Q2);
    bf16* k1   = (bf16*)(ws + OFF_K1);
    bf16* wqT  = (bf16*)(ws + OFF_WQT);
    bf16* wkT  = (bf16*)(ws + OFF_WKT);
    bf16* woT  = (bf16*)(ws + OFF_WOT);
    bf16* vwt  = (bf16*)(ws + OFF_VWT);
    float* accb = (float*)(ws + OFF_ACC);

    // flags + 3 weight transposes + accb zeroing + mode publish
    prep_kernel<<<3600, 256, 0, stream>>>(Wq, Wk, Wo, wqT, wkT, woT,
                                          ulb1, ulb2, flags, accb, modep, anchor);
    scan_kernel<<<2, 1024, 0, stream>>>(flags, sel, counts);
    buildq_kernel<<<dim3(KQ, 2), 128, 0, stream>>>(anchor, positive, lbfeat, lboh, ulb1, ulb2,
                                                   fq1i, fq2i, lq1i, lq2i, sel, counts,
                                                   fq1, fq2, lq1, lq2, modep);
    // q-proj (2 streams) + k-proj + VW^T in one launch
    gemm3_kernel<<<896, 256, 0, stream>>>(anchor, positive, fq1, woT, lq1, wqT, wkT,
                                          q1, q2, k1, vwt, modep);

    flash3_kernel<<<dim3(32, NHEAD, 2), 256, 0, stream>>>(q1, q2, k1, vwt, accb);
    bias_kernel<<<(2 * N_Q * NLAB) / 256, 256, 0, stream>>>(accb, bo, d_out, modep);
}

// Round 13
// 343.978 us; speedup vs baseline: 1.0431x; 1.0075x over previous
//
#include <hip/hip_runtime.h>

typedef __bf16 bf16;
typedef __bf16 bf16x8 __attribute__((ext_vector_type(8)));
typedef float f32x4 __attribute__((ext_vector_type(4)));

#define MFMA16(a,b,c) __builtin_amdgcn_mfma_f32_16x16x32_bf16(a,b,c,0,0,0)

#if __has_builtin(__builtin_amdgcn_exp2f)
#define EXP2(x) __builtin_amdgcn_exp2f(x)
#else
#define EXP2(x) exp2f(x)
#endif

// global -> LDS direct copy, 16B per lane; LDS dest is wave-uniform base + lane*16
#define GLOAD16(g, l) __builtin_amdgcn_global_load_lds( \
    (const __attribute__((address_space(1))) void*)(g), \
    (__attribute__((address_space(3))) void*)(l), 16, 0, 0)

#define N_Q   4096
#define DFEAT 512
#define KQ    8192
#define NLAB  128
#define NHEAD 8
#define KVB   32

// ---------------- workspace layout (bytes) ----------------
#define MBv (1024ull*1024ull)
#define OFF_COUNTS 0ull
#define OFF_MODE   512ull
#define OFF_FLAGS  1024ull
#define OFF_SEL    (64ull*1024ull)
#define OFF_FQ1    (1ull*MBv)   // 8192x512 bf16 = 8MB   (fq2 adjacent)
#define OFF_FQ2    (9ull*MBv)
#define OFF_LQ1    (17ull*MBv)  // 8192x128 bf16 = 2MB   (lq2 adjacent)
#define OFF_LQ2    (19ull*MBv)
#define OFF_Q1     (21ull*MBv)  // 4096x512 bf16 = 4MB
#define OFF_Q2     (25ull*MBv)
#define OFF_K1     (29ull*MBv)  // 16384x512 bf16 = 16MB (both streams)
#define OFF_WQT    (45ull*MBv)
#define OFF_WKT    (46ull*MBv)
#define OFF_WOT    (47ull*MBv)
#define OFF_VWT    (48ull*MBv)  // 128x16384 bf16 = 4MB (VW^T, natural layout, both streams)
#define OFF_ACC    (52ull*MBv)  // 2x4096x128 f32 = 4MB

// ---------------- inline dtype probe (used once, in prep) ----------------
__device__ __forceinline__ int probe_f32(const void* p) {
    const unsigned short* u = (const unsigned short*)p;
    int bad = 0;
    #pragma unroll
    for (int i = 0; i < 32; i++) {
        unsigned short v = u[2 * i];
        int e = (v >> 7) & 0xFF;
        if (e > 140 || (e < 60 && e != 0)) bad++;
    }
    return bad > 3;
}

// ---------------- dtype-agnostic loads ----------------
__device__ __forceinline__ float loads(const void* p, size_t i, int f32m) {
    return f32m ? ((const float*)p)[i] : (float)((const bf16*)p)[i];
}
__device__ __forceinline__ bf16x8 load8(const void* p, size_t i, int f32m) {
    bf16x8 r;
    if (f32m) {
        const float4* q = (const float4*)((const float*)p + i);
        float4 f0 = q[0], f1 = q[1];
        r[0] = (bf16)f0.x; r[1] = (bf16)f0.y; r[2] = (bf16)f0.z; r[3] = (bf16)f0.w;
        r[4] = (bf16)f1.x; r[5] = (bf16)f1.y; r[6] = (bf16)f1.z; r[7] = (bf16)f1.w;
    } else {
        r = *(const bf16x8*)((const bf16*)p + i);
    }
    return r;
}

// ---------------- prep: flags + transposes + accb zeroing + mode publish ----------------
// Grid: [0,2048) flags | [2048,2304) Wq | [2304,2560) Wk | [2560,2576) Wo | [2576,3600) zero accb
__device__ __forceinline__ void do_transpose(const void* W, bf16* T, int n,
                                             int bxi, int byi, int f32m, bf16 (*tile)[33]) {
    int bx = bxi * 32, by = byi * 32;
    int tx = threadIdx.x & 31, ty = threadIdx.x >> 5;
    for (int r = ty; r < 32; r += 8) tile[r][tx] = (bf16)loads(W, (size_t)(by + r) * n + bx + tx, f32m);
    __syncthreads();
    for (int r = ty; r < 32; r += 8) T[(size_t)(bx + r) * n + by + tx] = tile[tx][r];
}

__global__ void prep_kernel(const void* __restrict__ Wq, const void* __restrict__ Wk,
                            const void* __restrict__ Wo,
                            bf16* __restrict__ wqT, bf16* __restrict__ wkT, bf16* __restrict__ woT,
                            const void* __restrict__ ulb1, const void* __restrict__ ulb2,
                            int* __restrict__ flags, float* __restrict__ accb,
                            int* __restrict__ modep, const void* __restrict__ probe) {
    __shared__ bf16 tile[32][33];
    int b = blockIdx.x, t = threadIdx.x;
    if (b >= 2576) {                // zero accb: 1024 blocks x 256 thr x 1 float4
        float4 z = {0.f, 0.f, 0.f, 0.f};
        ((float4*)accb)[(size_t)(b - 2576) * 256 + t] = z;
        return;
    }
    int f32m = probe_f32(probe);
    if (b == 0 && t == 0) *modep = f32m;    // publish for downstream kernels
    if (b < 2048) {                 // flags: 4 rows per block (one per wave)
        int idx = b * 4 + (t >> 6); // [0, 8192)
        int lane = t & 63;
        int s = idx >> 12, row = idx & 4095;
        const void* p = s ? ulb2 : ulb1;
        size_t base = (size_t)row * NLAB;
        float m = fmaxf(loads(p, base + lane, f32m), loads(p, base + lane + 64, f32m));
        #pragma unroll
        for (int off = 32; off; off >>= 1) m = fmaxf(m, __shfl_xor(m, off));
        if (lane == 0) flags[s * N_Q + row] = (m > 0.95f) ? 1 : 0;
    } else if (b < 2304) {          // Wq: 16x16 blocks of 512^2
        int tb = b - 2048;
        do_transpose(Wq, wqT, 512, tb & 15, tb >> 4, f32m, tile);
    } else if (b < 2560) {          // Wk
        int tb = b - 2304;
        do_transpose(Wk, wkT, 512, tb & 15, tb >> 4, f32m, tile);
    } else {                        // Wo: 4x4 blocks of 128^2
        int tb = b - 2560;
        do_transpose(Wo, woT, 128, tb & 3, tb >> 2, f32m, tile);
    }
}

// ---------------- scan: stable compaction ----------------
__global__ void scan_kernel(const int* __restrict__ flags, int* __restrict__ sel,
                            int* __restrict__ counts) {
    int s = blockIdx.x, t = threadIdx.x; // 1024 threads
    const int* f = flags + s * N_Q;
    int* selp = sel + s * N_Q;
    __shared__ int ls[1024];
    int f0 = f[t*4], f1 = f[t*4+1], f2 = f[t*4+2], f3 = f[t*4+3];
    int local = f0 + f1 + f2 + f3;
    ls[t] = local;
    __syncthreads();
    for (int off = 1; off < 1024; off <<= 1) {
        int v = (t >= off) ? ls[t - off] : 0;
        __syncthreads();
        ls[t] += v;
        __syncthreads();
    }
    int pos = ls[t] - local;
    if (f0) selp[pos++] = t*4;
    if (f1) selp[pos++] = t*4+1;
    if (f2) selp[pos++] = t*4+2;
    if (f3) selp[pos++] = t*4+3;
    if (t == 1023) counts[s] = ls[1023];
}

// ---------------- build queues: 4 rows per 256-thread block ----------------
// Phase 1: all 256 threads copy feat (4 rows x 64 lanes x 16B).
// Phase 2: threads 0-63 copy labels (4 rows x 16 lanes x 16B).
__device__ __forceinline__ void resolve_row(int i, int s, int C,
                                            const void* anchor, const void* positive,
                                            const void* lbfeat, const void* lboh,
                                            const void* ulb1, const void* ulb2,
                                            const void* fq1i, const void* fq2i,
                                            const void* lq1i, const void* lq2i,
                                            const int* sel,
                                            const void** fb, size_t* frow,
                                            const void** lb, size_t* lrow) {
    if (i < C) {
        int r = sel[s * N_Q + i];
        *fb = s ? positive : anchor; *frow = r;
        *lb = s ? ulb2 : ulb1;       *lrow = r;
    } else if (i < C + 512) {
        int r = i - C + s * 512;
        *fb = lbfeat; *frow = r;
        *lb = lboh;   *lrow = r;
    } else {
        int r = i - C - 512;
        *fb = s ? fq2i : fq1i; *frow = r;
        *lb = s ? lq2i : lq1i; *lrow = r;
    }
}

__global__ void buildq_kernel(const void* __restrict__ anchor, const void* __restrict__ positive,
                              const void* __restrict__ lbfeat, const void* __restrict__ lboh,
                              const void* __restrict__ ulb1, const void* __restrict__ ulb2,
                              const void* __restrict__ fq1i, const void* __restrict__ fq2i,
                              const void* __restrict__ lq1i, const void* __restrict__ lq2i,
                              const int* __restrict__ sel, const int* __restrict__ counts,
                              bf16* __restrict__ fq1o, bf16* __restrict__ fq2o,
                              bf16* __restrict__ lq1o, bf16* __restrict__ lq2o,
                              const int* __restrict__ modep) {
    int f32m = *modep;
    int s = blockIdx.y, t = threadIdx.x; // 2048 blocks x 256 threads, 4 rows/block
    int C = counts[s];
    bf16* fqo = s ? fq2o : fq1o;
    bf16* lqo = s ? lq2o : lq1o;

    // phase 1: feat rows
    {
        int sub = t >> 6, lane = t & 63;
        int i = blockIdx.x * 4 + sub;
        const void *fb, *lb; size_t frow, lrow;
        resolve_row(i, s, C, anchor, positive, lbfeat, lboh, ulb1, ulb2,
                    fq1i, fq2i, lq1i, lq2i, sel, &fb, &frow, &lb, &lrow);
        *(bf16x8*)&fqo[(size_t)i * DFEAT + lane * 8] = load8(fb, frow * DFEAT + (size_t)lane * 8, f32m);
    }
    // phase 2: label rows (threads 0-63)
    if (t < 64) {
        int sub = t >> 4, l16 = t & 15;
        int i = blockIdx.x * 4 + sub;
        const void *fb, *lb; size_t frow, lrow;
        resolve_row(i, s, C, anchor, positive, lbfeat, lboh, ulb1, ulb2,
                    fq1i, fq2i, lq1i, lq2i, sel, &fb, &frow, &lb, &lrow);
        *(bf16x8*)&lqo[(size_t)i * NLAB + l16 * 8] = load8(lb, lrow * NLAB + (size_t)l16 * 8, f32m);
    }
}

// ---------------- merged GEMM: q-proj (2 streams) + k-proj + VW^T in one launch ----------------
__device__ __forceinline__ void gemm_body(const void* __restrict__ A, const bf16* __restrict__ B,
                                          bf16* __restrict__ C, int N, int Kd, float alpha,
                                          int f32m, int m0, int n0,
                                          bf16* As, bf16* Bs) {
    int t = threadIdx.x, lane = t & 63, wid = t >> 6;
    int quad = lane >> 4, l15 = lane & 15;
    int wrow = (wid >> 1) * 64, wcol = (wid & 1) * 64;
    int srow = t >> 1, sseg = t & 1;
    f32x4 acc[4][4] = {};
    for (int k0 = 0; k0 < Kd; k0 += 32) {
        __syncthreads();
        bf16x8 a0 = load8(A, (size_t)(m0 + srow) * Kd + k0 + sseg * 8, f32m);
        bf16x8 a1 = load8(A, (size_t)(m0 + srow) * Kd + k0 + (sseg + 2) * 8, f32m);
        const uint4* gb = (const uint4*)(B + (size_t)(n0 + srow) * Kd + k0);
        uint4 b0 = gb[sseg], b1 = gb[sseg + 2];
        *(bf16x8*)&As[srow * 72 + sseg * 8]       = a0;
        *(bf16x8*)&As[srow * 72 + (sseg + 2) * 8] = a1;
        *(uint4*)&Bs[srow * 72 + sseg * 8]        = b0;
        *(uint4*)&Bs[srow * 72 + (sseg + 2) * 8]  = b1;
        __syncthreads();
        bf16x8 af[4], bfr[4];
        #pragma unroll
        for (int mt = 0; mt < 4; mt++) af[mt]  = *(const bf16x8*)&As[(wrow + mt*16 + l15) * 72 + quad * 8];
        #pragma unroll
        for (int nt = 0; nt < 4; nt++) bfr[nt] = *(const bf16x8*)&Bs[(wcol + nt*16 + l15) * 72 + quad * 8];
        #pragma unroll
        for (int mt = 0; mt < 4; mt++)
            #pragma unroll
            for (int nt = 0; nt < 4; nt++)
                acc[mt][nt] = MFMA16(af[mt], bfr[nt], acc[mt][nt]);
    }
    #pragma unroll
    for (int mt = 0; mt < 4; mt++)
        #pragma unroll
        for (int nt = 0; nt < 4; nt++)
            #pragma unroll
            for (int r = 0; r < 4; r++) {
                int row = m0 + wrow + mt*16 + quad*4 + r;
                int col = n0 + wcol + nt*16 + l15;
                C[(size_t)row * N + col] = (bf16)(acc[mt][nt][r] * alpha);
            }
}

// Grid: [0,256) q-proj | [256,768) k-proj | [768,896) VW^T
__launch_bounds__(256, 3)
__global__ void gemm3_kernel(const void* __restrict__ anchor, const void* __restrict__ positive,
                             const bf16* __restrict__ fq1, const bf16* __restrict__ woT,
                             const bf16* __restrict__ lq1,
                             const bf16* __restrict__ wqT, const bf16* __restrict__ wkT,
                             bf16* __restrict__ q1, bf16* __restrict__ q2,
                             bf16* __restrict__ k1, bf16* __restrict__ vwt,
                             const int* __restrict__ modep) {
    __shared__ __align__(16) bf16 As[128 * 72];
    __shared__ __align__(16) bf16 Bs[128 * 72];
    int b = blockIdx.x;
    if (b < 256) {
        int f32m = *modep;
        int s = b >> 7, r = b & 127;
        gemm_body(s ? positive : anchor, wqT, s ? q2 : q1, 512, 512,
                  0.125f * 1.44269504088896f, f32m, (r >> 2) * 128, (r & 3) * 128, As, Bs);
    } else if (b < 768) {
        int r = b - 256;
        gemm_body(fq1, wkT, k1, 512, 512, 1.0f, 0, (r >> 2) * 128, (r & 3) * 128, As, Bs);
    } else {
        int r = b - 768;
        gemm_body(woT, lq1, vwt, 16384, 128, 1.0f, 0, 0, r * 128, As, Bs);
    }
}

// ---------------- flash v6 (R6-exact, proven ~192us): 64-row waves + kv-split pairs ----------
__launch_bounds__(256, 2)
__global__ void flash3_kernel(const bf16* __restrict__ q1, const bf16* __restrict__ q2,
                              const bf16* __restrict__ kbase, const bf16* __restrict__ vbase,
                              float* __restrict__ acc_out) {
    __shared__ __align__(16) char smem[49152];   // 16KB K (2 half x 2 buf x 4KB) + 32KB V (2x2x8KB)
    int qb = blockIdx.x, h = blockIdx.y, s = blockIdx.z;
    const bf16* Q  = s ? q2 : q1;
    const bf16* Kp = kbase + (size_t)s * KQ * DFEAT + h * 64;
    const bf16* Vp = vbase + (size_t)s * KQ;          // row pitch 2*KQ
    int t = threadIdx.x, lane = t & 63, wid = t >> 6;
    int quad = lane >> 4, l15 = lane & 15;
    int wq = wid & 1, wh = wid >> 1;
    int qbase = qb * 128 + wq * 64;

    // Q B-frags in registers for whole kernel (4 m-tiles x 2 feat chunks)
    bf16x8 qf[4][2];
    #pragma unroll
    for (int mt = 0; mt < 4; mt++)
        #pragma unroll
        for (int ch = 0; ch < 2; ch++)
            qf[mt][ch] = *(const bf16x8*)(Q + (size_t)(qbase + mt*16 + l15) * DFEAT + h*64 + ch*32 + quad*8);

    bf16x8 onesf;
    #pragma unroll
    for (int i = 0; i < 8; i++) onesf[i] = (bf16)1.0f;

    // LDS tile bases
    bf16* Kt = (bf16*)smem;            // tile stride 2048 elems (4KB)
    bf16* Vt = (bf16*)(smem + 16384);  // tile stride 4096 elems (8KB)

    // staging lane constants: linear LDS slot = lane&7 of row lane>>3; logical slot = lslot ^ (row&7)
    int srow8 = lane >> 3;
    int sslot = (lane & 7) ^ srow8;
    const bf16* KgH = Kp + (size_t)(wh * 4096) * DFEAT + (size_t)srow8 * DFEAT + sslot * 8;
    const bf16* VgH = Vp + wh * 4096 + (size_t)(2*srow8 + (sslot >> 2)) * (2 * KQ) + (sslot & 3) * 8;

    // read offset maps
    const int h7 = l15 & 7;
    int kro[2][2], vro[8];
    #pragma unroll
    for (int nt = 0; nt < 2; nt++)
        #pragma unroll
        for (int ch = 0; ch < 2; ch++)
            kro[nt][ch] = (nt*16 + l15) * 64 + (((ch*4 + quad) ^ h7) << 3);
    #pragma unroll
    for (int ct = 0; ct < 8; ct++)
        vro[ct] = (ct*8 + (l15 >> 1)) * 64 + (((((l15 & 1) << 2) | quad) ^ (l15 >> 1)) << 3);

    // prologue: stage it=0 into buf 0
    {
        bf16* kb = Kt + (size_t)(wh*2 + 0) * 2048;
        bf16* vb = Vt + (size_t)(wh*2 + 0) * 4096;
        if (wq == 0) {
            #pragma unroll
            for (int c = 0; c < 4; c++) GLOAD16(KgH + (size_t)c*8*DFEAT, kb + c*512);
            #pragma unroll
            for (int c = 0; c < 2; c++) GLOAD16(VgH + (size_t)c*16*(2*KQ), vb + c*512);
        } else {
            #pragma unroll
            for (int c = 2; c < 8; c++) GLOAD16(VgH + (size_t)c*16*(2*KQ), vb + c*512);
        }
    }
    __syncthreads();

    f32x4 O[4][8] = {};
    f32x4 L[4] = {};

    for (int it = 0; it < 4096 / KVB; it++) {
        int p = it & 1;
        // stage next iter into other buffer (loads complete before next barrier's vmcnt(0))
        if (it + 1 < 4096 / KVB) {
            int kvn = (it + 1) * KVB;
            bf16* kb = Kt + (size_t)(wh*2 + (p^1)) * 2048;
            bf16* vb = Vt + (size_t)(wh*2 + (p^1)) * 4096;
            if (wq == 0) {
                #pragma unroll
                for (int c = 0; c < 4; c++) GLOAD16(KgH + (size_t)kvn*DFEAT + (size_t)c*8*DFEAT, kb + c*512);
                #pragma unroll
                for (int c = 0; c < 2; c++) GLOAD16(VgH + kvn + (size_t)c*16*(2*KQ), vb + c*512);
            } else {
                #pragma unroll
                for (int c = 2; c < 8; c++) GLOAD16(VgH + kvn + (size_t)c*16*(2*KQ), vb + c*512);
            }
        }
        const bf16* Kb = Kt + (size_t)(wh*2 + p) * 2048;
        const bf16* Vb = Vt + (size_t)(wh*2 + p) * 4096;

        // K fragments (full 32x64 tile)
        bf16x8 kf[2][2];
        #pragma unroll
        for (int nt = 0; nt < 2; nt++)
            #pragma unroll
            for (int ch = 0; ch < 2; ch++)
                kf[nt][ch] = *(const bf16x8*)&Kb[kro[nt][ch]];

        // QK + exp fused per mt: S^T = K . Q^T, D[m=kv][n=q]
        bf16x8 P[4];
        __builtin_amdgcn_s_setprio(1);
        #pragma unroll
        for (int mt = 0; mt < 4; mt++) {
            f32x4 s0 = {}, s1 = {};
            s0 = MFMA16(kf[0][0], qf[mt][0], s0);
            s0 = MFMA16(kf[0][1], qf[mt][1], s0);
            s1 = MFMA16(kf[1][0], qf[mt][0], s1);
            s1 = MFMA16(kf[1][1], qf[mt][1], s1);
            bf16x8 pp;
            #pragma unroll
            for (int r = 0; r < 4; r++) {
                pp[r]     = (bf16)EXP2(s0[r]);
                pp[4 + r] = (bf16)EXP2(s1[r]);
            }
            P[mt] = pp;
        }
        // row-sums via ones-MFMA
        #pragma unroll
        for (int mt = 0; mt < 4; mt++) L[mt] = MFMA16(P[mt], onesf, L[mt]);
        // O += P . VW  (V frags JIT from LDS)
        #pragma unroll
        for (int ct = 0; ct < 8; ct++) {
            bf16x8 vf = *(const bf16x8*)&Vb[vro[ct]];
            #pragma unroll
            for (int mt = 0; mt < 4; mt++)
                O[mt][ct] = MFMA16(P[mt], vf, O[mt][ct]);
        }
        __builtin_amdgcn_s_setprio(0);
        __syncthreads();
    }

    // merge kv-halves through LDS (two passes to fit 48KB), then normalize + atomicAdd
    f32x4* MP = (f32x4*)smem;
    int midx = lane * 36;
    #pragma unroll
    for (int pass = 0; pass < 2; pass++) {
        if (wh == 1 && wq == pass) {
            #pragma unroll
            for (int mt = 0; mt < 4; mt++) {
                #pragma unroll
                for (int ct = 0; ct < 8; ct++) MP[midx + mt*8 + ct] = O[mt][ct];
                MP[midx + 32 + mt] = L[mt];
            }
        }
        __syncthreads();
        if (wh == 0 && wq == pass) {
            #pragma unroll
            for (int mt = 0; mt < 4; mt++) {
                f32x4 lp = MP[midx + 32 + mt];
                float invr[4];
                #pragma unroll
                for (int r = 0; r < 4; r++) invr[r] = 1.0f / (8.0f * (L[mt][r] + lp[r]));
                #pragma unroll
                for (int ct = 0; ct < 8; ct++) {
                    f32x4 op = MP[midx + mt*8 + ct];
                    #pragma unroll
                    for (int r = 0; r < 4; r++) {
                        int row = qbase + mt*16 + quad*4 + r;
                        atomicAdd(&acc_out[((size_t)s * N_Q + row) * NLAB + ct*16 + l15],
                                  (O[mt][ct][r] + op[r]) * invr[r]);
                    }
                }
            }
        }
        __syncthreads();
    }
}

// ---------------- bias + cast: float4 per thread ----------------
__global__ void bias_kernel(const float* __restrict__ acc, const void* __restrict__ bo,
                            void* __restrict__ out, const int* __restrict__ modep) {
    int f32m = *modep;
    int idx4 = blockIdx.x * 256 + threadIdx.x;   // float4 index
    float4 a = ((const float4*)acc)[idx4];
    int lb = (idx4 * 4) & (NLAB - 1);
    float4 v;
    v.x = a.x + loads(bo, lb + 0, f32m);
    v.y = a.y + loads(bo, lb + 1, f32m);
    v.z = a.z + loads(bo, lb + 2, f32m);
    v.w = a.w + loads(bo, lb + 3, f32m);
    if (f32m) {
        ((float4*)out)[idx4] = v;
    } else {
        bf16* o = (bf16*)out + (size_t)idx4 * 4;
        o[0] = (bf16)v.x; o[1] = (bf16)v.y; o[2] = (bf16)v.z; o[3] = (bf16)v.w;
    }
}

extern "C" void kernel_launch(void* const* d_in, const int* in_sizes, int n_in,
                              void* d_out, int out_size, void* d_ws, size_t ws_size,
                              hipStream_t stream) {
    const void* anchor   = d_in[0];
    const void* positive = d_in[1];
    const void* lbfeat   = d_in[2];
    const void* lboh     = d_in[3];
    const void* ulb1     = d_in[5];
    const void* ulb2     = d_in[6];
    const void* fq1i     = d_in[7];
    const void* fq2i     = d_in[8];
    const void* lq1i     = d_in[9];
    const void* lq2i     = d_in[10];
    const void* Wq       = d_in[11];
    const void* Wk       = d_in[12];
    const void* Wo       = d_in[13];
    const void* bo       = d_in[14];

    char* ws = (char*)d_ws;
    int*  counts = (int*)(ws + OFF_COUNTS);
    int*  modep  = (int*)(ws + OFF_MODE);
    int*  flags  = (int*)(ws + OFF_FLAGS);
    int*  sel    = (int*)(ws + OFF_SEL);
    bf16* fq1  = (bf16*)(ws + OFF_FQ1);
    bf16* fq2  = (bf16*)(ws + OFF_FQ2);
    bf16* lq1  = (bf16*)(ws + OFF_LQ1);
    bf16* lq2  = (bf16*)(ws + OFF_LQ2);
    bf16* q1   = (bf16*)(ws + OFF_Q1);
    bf16* q2   = (bf16*)(ws + OFF_Q2);
    bf16* k1   = (bf16*)(ws + OFF_K1);
    bf16* wqT  = (bf16*)(ws + OFF_WQT);
    bf16* wkT  = (bf16*)(ws + OFF_WKT);
    bf16* woT  = (bf16*)(ws + OFF_WOT);
    bf16* vwt  = (bf16*)(ws + OFF_VWT);
    float* accb = (float*)(ws + OFF_ACC);

    // flags + 3 weight transposes + accb zeroing + mode publish
    prep_kernel<<<3600, 256, 0, stream>>>(Wq, Wk, Wo, wqT, wkT, woT,
                                          ulb1, ulb2, flags, accb, modep, anchor);
    scan_kernel<<<2, 1024, 0, stream>>>(flags, sel, counts);
    // 4 rows per block: 2048 x 2 blocks of 256 threads
    buildq_kernel<<<dim3(KQ / 4, 2), 256, 0, stream>>>(anchor, positive, lbfeat, lboh, ulb1, ulb2,
                                                       fq1i, fq2i, lq1i, lq2i, sel, counts,
                                                       fq1, fq2, lq1, lq2, modep);
    // q-proj (2 streams) + k-proj + VW^T in one launch
    gemm3_kernel<<<896, 256, 0, stream>>>(anchor, positive, fq1, woT, lq1, wqT, wkT,
                                          q1, q2, k1, vwt, modep);

    flash3_kernel<<<dim3(32, NHEAD, 2), 256, 0, stream>>>(q1, q2, k1, vwt, accb);
    bias_kernel<<<(2 * N_Q * NLAB) / 1024, 256, 0, stream>>>(accb, bo, d_out, modep);
}